// Round 17
// baseline (3302.028 us; speedup 1.0000x reference)
//
#include <hip/hip_runtime.h>

typedef float v2f __attribute__((ext_vector_type(2)));
typedef float v4f __attribute__((ext_vector_type(4)));

constexpr int T  = 1024;
constexpr int B  = 32;
constexpr int I_ = 64;
constexpr int H  = 1024;
constexpr int OF = 64;
constexpr int OC = 8;
constexpr int NG = 16;   // groups (2 batches each)
constexpr int NM = 16;   // member WGs per group (64 rows each)
constexpr int CH  = 136; // per-lane contiguous k-chunk (1088/8)
constexpr int CHP = 140; // padded chunk stride (12*l8 mod 32 -> all banks)
constexpr int BSTR = 8 * CHP;
constexpr long long OUT1_OFF = (long long)T * B * OF;
constexpr long long OUT2_OFF = (long long)T * B * (OF + OC);
constexpr int RING_U64 = NG * 4 * 2 * 1024;  // [g][slot(4)][b][row] = 1 MB

// Agent-scope relaxed ops: global_{load,store} sc0 sc1 — bypass L1/L2,
// coherent at L3 (stores also land in L3 -> polls are L3 hits; R2's FETCH
// proves 96% of agent re-reads were L3-served). Proven medium.
// sc0-only polling livelocks (R4/R5/R7) — never used.
__device__ __forceinline__ void st_agent_f32(float* p, float v) {
  __hip_atomic_store(p, v, __ATOMIC_RELAXED, __HIP_MEMORY_SCOPE_AGENT);
}
__device__ __forceinline__ void st_agent_u64(unsigned long long* p,
                                             unsigned long long v) {
  __hip_atomic_store(p, v, __ATOMIC_RELAXED, __HIP_MEMORY_SCOPE_AGENT);
}
__device__ __forceinline__ unsigned long long
ld_agent_u64(const unsigned long long* p) {
  return __hip_atomic_load(p, __ATOMIC_RELAXED, __HIP_MEMORY_SCOPE_AGENT);
}

// ---------------------------------------------------------------------------
// Recurrence: 256 persistent WGs x 512 threads (1/CU). R16 structure with
// PROBE TIMING FIXED (the R11-R16 comment "L1 stored a full step ago" was
// WRONG — C1(t-1) stores land at the very END of step t-1, so the top-of-
// step L1 issue sampled ~0.1us after the store, inside the visibility
// window, went stale, and paid a serial re-poll RT at the check EVERY step):
//  - L1 probe issues INSIDE C0 at ~1/3 (sample ~0.3us after its producer
//    store — past visibility), second sample at ~2/3 (DUAL SAMPLING: the
//    check tries s1, then s2 already in flight, then the proven re-poll —
//    stale penalty bounded by the sample spacing instead of a full RT).
//  - L0 probe likewise dual-samples at q=9 and q=21 of C1.
// Check positions and commit points unchanged from R10-R16 => the same
// liveness/lap-safety induction applies (4-slot ring, lgkm-only barriers,
// data-dependence-carried ordering). Ring zeroed per call (tags >= 1).
// ---------------------------------------------------------------------------
__global__ __launch_bounds__(512, 1) void rnn_recur(
    const float* __restrict__ input_sig, const float* __restrict__ rate0,
    const float* __restrict__ i2h_w, const float* __restrict__ i2h_b,
    const float* __restrict__ h2h_w, const float* __restrict__ h2h_b,
    float* __restrict__ rate_all, unsigned long long* __restrict__ ring)
{
  const int tid = threadIdx.x;
  const int bid = blockIdx.x;
  const int g   = bid & (NG - 1);
  const int m   = bid >> 4;
  const int l8  = tid & 7;
  const int jrel = tid >> 3;
  const int j   = m * 64 + jrel;
  const int bG  = g * 2;

  __shared__ float lds[2][BSTR];   // [batch][padded chunks]

  // ---- stationary weights: 68 float2 = 136 fp32/thread
  v2f w2[68];
#pragma unroll
  for (int q = 0; q < 68; ++q) {
    const int k = l8 * CH + q * 2;
    w2[q] = (k < H) ? *(const v2f*)(h2h_w + (long long)j * H + k)
                    : *(const v2f*)(i2h_w + (long long)j * I_ + (k - H));
  }
  const float bsum = h2h_b[j] + i2h_b[j];
  const int posj = (j / CH) * CHP + (j % CH);

  // ---- init: r_{-1} = rate0 and x_0 for both batches (plain cached loads)
  {
    const int b = tid >> 8, u4 = tid & 255;
    const int k0 = u4 * 4, c = k0 / CH, off = k0 - c * CH;
    float4 v = *(const float4*)(rate0 + (long long)(bG + b) * H + k0);
    *(float4*)&lds[b][c * CHP + off] = v;
    if (tid < 32) {
      const int b2 = tid >> 4, iq = tid & 15;
      float4 u = *(const float4*)(input_sig + (long long)(bG + b2) * I_ + iq * 4);
      *(float4*)&lds[b2][7 * CHP + 72 + iq * 4] = u;
    }
  }
  __syncthreads();

  unsigned long long* ringG = ring + (long long)g * (4 * 2 * 1024);
  const int c_  = (2 * tid) / CH;
  const int off_ = 2 * tid - c_ * CH;

#define FMA_Q(RB_, Q_) {                                            \
    const v4f rv = *(const v4f*)&(RB_)[l8 * CHP + (Q_) * 4];        \
    const v2f rlo = __builtin_shufflevector(rv, rv, 0, 1);          \
    const v2f rhi = __builtin_shufflevector(rv, rv, 2, 3);          \
    acc2 = __builtin_elementwise_fma(w2[2 * (Q_)],     rlo, acc2);  \
    acc2 = __builtin_elementwise_fma(w2[2 * (Q_) + 1], rhi, acc2);  \
  }

  for (int t = 0; t < T; ++t) {
    // =================== phase 0: batch 0, dual-sampled L1 ===============
    const bool have1 = (t > 0);
    const bool have0 = (t + 1 < T);
    const unsigned long long* p1 =
        &ringG[((long long)((((t - 1) & 3) * 2) + 1) << 10) + 2 * tid];
    unsigned long long s1a = 0, s1b = 0, s1c = 0, s1d = 0;
    float4 xv1;
    {
      const float* Rb = &lds[0][0];
      v2f acc2 = {0.f, 0.f};
#pragma unroll
      for (int q = 0; q < 10; ++q) FMA_Q(Rb, q)
      if (have1) { s1a = ld_agent_u64(p1); s1b = ld_agent_u64(p1 + 1); }
      __builtin_amdgcn_sched_barrier(0);      // pin sample-1 issue (~1/3)
#pragma unroll
      for (int q = 10; q < 22; ++q) FMA_Q(Rb, q)
      if (have1) {
        s1c = ld_agent_u64(p1); s1d = ld_agent_u64(p1 + 1);
        if (tid < 16) {
          xv1 = *(const float4*)(input_sig +
              ((long long)t * B + bG + 1) * I_ + tid * 4);
        }
      }
      __builtin_amdgcn_sched_barrier(0);      // pin sample-2 issue (~2/3)
#pragma unroll
      for (int q = 22; q < 34; ++q) FMA_Q(Rb, q)
      float acc = acc2.x + acc2.y;
      acc += __shfl_xor(acc, 4, 64);
      acc += __shfl_xor(acc, 2, 64);
      acc += __shfl_xor(acc, 1, 64);
      if (l8 == 0) {
        const float pre  = acc + bsum;
        const float rold = Rb[posj];
        const float rnew = 0.9f * rold + 0.1f * tanhf(pre);
        const unsigned long long pkt =
            ((unsigned long long)(unsigned)(t + 1) << 32) |
            (unsigned long long)__float_as_uint(rnew);
        st_agent_u64(&ringG[((long long)((t & 3) * 2) << 10) + j], pkt);
        st_agent_f32(&rate_all[((long long)t * B + bG) * H + j], rnew);
      }
    }
    // ---- check L1: s1, else s2 (in flight), else re-poll
    if (have1) {
      const unsigned tag = (unsigned)t;
      unsigned long long va, vb;
      if ((unsigned)(s1a >> 32) == tag && (unsigned)(s1b >> 32) == tag) {
        va = s1a; vb = s1b;
      } else if ((unsigned)(s1c >> 32) == tag && (unsigned)(s1d >> 32) == tag) {
        va = s1c; vb = s1d;
      } else {
        va = ld_agent_u64(p1); vb = ld_agent_u64(p1 + 1);
        while ((unsigned)(va >> 32) != tag || (unsigned)(vb >> 32) != tag) {
          va = ld_agent_u64(p1); vb = ld_agent_u64(p1 + 1);
        }
      }
      *(float2*)&lds[1][c_ * CHP + off_] = make_float2(
          __uint_as_float((unsigned)va), __uint_as_float((unsigned)vb));
      if (tid < 16) *(float4*)&lds[1][7 * CHP + 72 + tid * 4] = xv1;
    }
    asm volatile("s_waitcnt lgkmcnt(0)\n\ts_barrier" ::: "memory");
    __builtin_amdgcn_sched_barrier(0);

    // =================== phase 1: batch 1, dual-sampled L0 ===============
    const unsigned long long* p0 =
        &ringG[((long long)((t & 3) * 2) << 10) + 2 * tid];
    unsigned long long s0a = 0, s0b = 0, s0c = 0, s0d = 0;
    float4 xv0;
    {
      const float* Rb = &lds[1][0];
      v2f acc2 = {0.f, 0.f};
#pragma unroll
      for (int q = 0; q < 9; ++q) FMA_Q(Rb, q)
      if (have0) { s0a = ld_agent_u64(p0); s0b = ld_agent_u64(p0 + 1); }
      __builtin_amdgcn_sched_barrier(0);      // pin sample-1 issue
#pragma unroll
      for (int q = 9; q < 21; ++q) FMA_Q(Rb, q)
      if (have0) {
        s0c = ld_agent_u64(p0); s0d = ld_agent_u64(p0 + 1);
        if (tid < 16) {
          xv0 = *(const float4*)(input_sig +
              ((long long)(t + 1) * B + bG) * I_ + tid * 4);
        }
      }
      __builtin_amdgcn_sched_barrier(0);      // pin sample-2 issue
#pragma unroll
      for (int q = 21; q < 34; ++q) FMA_Q(Rb, q)
      float acc = acc2.x + acc2.y;
      acc += __shfl_xor(acc, 4, 64);
      acc += __shfl_xor(acc, 2, 64);
      acc += __shfl_xor(acc, 1, 64);
      if (l8 == 0) {
        const float pre  = acc + bsum;
        const float rold = Rb[posj];
        const float rnew = 0.9f * rold + 0.1f * tanhf(pre);
        const unsigned long long pkt =
            ((unsigned long long)(unsigned)(t + 1) << 32) |
            (unsigned long long)__float_as_uint(rnew);
        st_agent_u64(&ringG[((long long)((t & 3) * 2 + 1) << 10) + j], pkt);
        st_agent_f32(&rate_all[((long long)t * B + bG + 1) * H + j], rnew);
      }
    }
    // ---- check L0: s1, else s2, else re-poll
    if (have0) {
      const unsigned tag = (unsigned)(t + 1);
      unsigned long long va, vb;
      if ((unsigned)(s0a >> 32) == tag && (unsigned)(s0b >> 32) == tag) {
        va = s0a; vb = s0b;
      } else if ((unsigned)(s0c >> 32) == tag && (unsigned)(s0d >> 32) == tag) {
        va = s0c; vb = s0d;
      } else {
        va = ld_agent_u64(p0); vb = ld_agent_u64(p0 + 1);
        while ((unsigned)(va >> 32) != tag || (unsigned)(vb >> 32) != tag) {
          va = ld_agent_u64(p0); vb = ld_agent_u64(p0 + 1);
        }
      }
      *(float2*)&lds[0][c_ * CHP + off_] = make_float2(
          __uint_as_float((unsigned)va), __uint_as_float((unsigned)vb));
      if (tid < 16) *(float4*)&lds[0][7 * CHP + 72 + tid * 4] = xv0;
    }
    asm volatile("s_waitcnt lgkmcnt(0)\n\ts_barrier" ::: "memory");
    __builtin_amdgcn_sched_barrier(0);
  }
#undef FMA_Q
}

// ---------------------------------------------------------------------------
// Readout: C[32768,72] = rate_all[32768,1024] x [h2o_w;h2o_ctx_w]^T + bias
// ---------------------------------------------------------------------------
__global__ __launch_bounds__(256) void rnn_readout(
    const float* __restrict__ rate_all,
    const float* __restrict__ h2o_w, const float* __restrict__ h2o_b,
    const float* __restrict__ h2o_ctx_w, const float* __restrict__ h2o_ctx_b,
    float* __restrict__ out0, float* __restrict__ out1)
{
  constexpr int RB = 128;
  constexpr int HC = 128;
  constexpr int SR = HC + 1;
  __shared__ float rl[RB * SR];
  __shared__ float wl[72 * SR];

  const int tid = threadIdx.x;
  const long long row0 = (long long)blockIdx.x * RB;
  const int rb = tid & 31, og = tid >> 5;

  float acc[4][9];
#pragma unroll
  for (int c = 0; c < 4; ++c)
#pragma unroll
    for (int i = 0; i < 9; ++i) acc[c][i] = 0.f;

  for (int hc = 0; hc < H / HC; ++hc) {
#pragma unroll
    for (int i = 0; i < 16; ++i) {
      const int q = i * 256 + tid;
      const int row = q >> 5, hq = q & 31;
      float4 v = *(const float4*)(rate_all + (row0 + row) * H + hc * HC + hq * 4);
      float* d = &rl[row * SR + hq * 4];
      d[0] = v.x; d[1] = v.y; d[2] = v.z; d[3] = v.w;
    }
#pragma unroll
    for (int i = 0; i < 9; ++i) {
      const int q = i * 256 + tid;
      const int o = q >> 5, hq = q & 31;
      const float* src = (o < OF) ? (h2o_w + (long long)o * H)
                                  : (h2o_ctx_w + (long long)(o - OF) * H);
      float4 v = *(const float4*)(src + hc * HC + hq * 4);
      float* d = &wl[o * SR + hq * 4];
      d[0] = v.x; d[1] = v.y; d[2] = v.z; d[3] = v.w;
    }
    __syncthreads();

#pragma unroll 4
    for (int h = 0; h < HC; ++h) {
      const float r0 = rl[(rb)      * SR + h];
      const float r1 = rl[(rb + 32) * SR + h];
      const float r2 = rl[(rb + 64) * SR + h];
      const float r3 = rl[(rb + 96) * SR + h];
#pragma unroll
      for (int i = 0; i < 9; ++i) {
        const float wv = wl[(og * 9 + i) * SR + h];
        acc[0][i] = fmaf(r0, wv, acc[0][i]);
        acc[1][i] = fmaf(r1, wv, acc[1][i]);
        acc[2][i] = fmaf(r2, wv, acc[2][i]);
        acc[3][i] = fmaf(r3, wv, acc[3][i]);
      }
    }
    __syncthreads();
  }

#pragma unroll
  for (int c = 0; c < 4; ++c) {
    const long long row = row0 + rb + 32 * c;
#pragma unroll
    for (int i = 0; i < 9; ++i) {
      const int o = og * 9 + i;
      if (o < OF) out0[row * OF + o] = acc[c][i] + h2o_b[o];
      else        out1[row * OC + (o - OF)] = acc[c][i] + h2o_ctx_b[o - OF];
    }
  }
}

extern "C" void kernel_launch(void* const* d_in, const int* in_sizes, int n_in,
                              void* d_out, int out_size, void* d_ws, size_t ws_size,
                              hipStream_t stream) {
  (void)in_sizes; (void)n_in; (void)d_ws; (void)ws_size; (void)out_size;
  const float* input_sig = (const float*)d_in[0];
  const float* rate0     = (const float*)d_in[1];
  const float* i2h_w     = (const float*)d_in[2];
  const float* i2h_b     = (const float*)d_in[3];
  const float* h2h_w     = (const float*)d_in[4];
  const float* h2h_b     = (const float*)d_in[5];
  const float* h2o_w     = (const float*)d_in[6];
  const float* h2o_b     = (const float*)d_in[7];
  const float* h2o_ctx_w = (const float*)d_in[8];
  const float* h2o_ctx_b = (const float*)d_in[9];

  float* out      = (float*)d_out;
  float* out0     = out;
  float* out1     = out + OUT1_OFF;
  float* rate_all = out + OUT2_OFF;
  // Tagged 4-slot ring in the first 1 MB of out0 (overwritten by readout).
  unsigned long long* ring = (unsigned long long*)d_out;

  // Zero the ring EVERY call: expected tags are >=1, so zero never matches;
  // stale tags from a previous call/graph-replay would otherwise alias.
  hipMemsetAsync(ring, 0, (size_t)RING_U64 * 8, stream);
  hipLaunchKernelGGL(rnn_recur, dim3(NG * NM), dim3(512), 0, stream,
                     input_sig, rate0, i2h_w, i2h_b, h2h_w, h2h_b,
                     rate_all, ring);
  hipLaunchKernelGGL(rnn_readout, dim3(256), dim3(256), 0, stream,
                     rate_all, h2o_w, h2o_b, h2o_ctx_w, h2o_ctx_b, out0, out1);
}

// Round 18
// 2889.827 us; speedup vs baseline: 1.1426x; 1.1426x over previous
//
#include <hip/hip_runtime.h>

typedef float v2f __attribute__((ext_vector_type(2)));
typedef float v4f __attribute__((ext_vector_type(4)));

constexpr int T  = 1024;
constexpr int B  = 32;
constexpr int I_ = 64;
constexpr int H  = 1024;
constexpr int OF = 64;
constexpr int OC = 8;
constexpr int NG = 16;   // groups (2 batches each)
constexpr int NM = 16;   // member WGs per group (64 rows each)
constexpr int CH  = 136; // per-lane contiguous k-chunk (1088/8)
constexpr int CHP = 140; // padded chunk stride (12*l8 mod 32 -> all banks)
constexpr int BSTR = 8 * CHP;
constexpr long long OUT1_OFF = (long long)T * B * OF;
constexpr long long OUT2_OFF = (long long)T * B * (OF + OC);
constexpr int RING_U64 = NG * 4 * 2 * 1024;  // [g][slot(4)][b][row] = 1 MB

// Agent-scope relaxed ops: global_{load,store} sc0 sc1 — bypass L1/L2,
// coherent at L3, fence-free. Proven medium (R2/R6/R10/R11/R14-R16).
// sc0-only polling livelocks (R4/R5/R7) — never used.
__device__ __forceinline__ void st_agent_f32(float* p, float v) {
  __hip_atomic_store(p, v, __ATOMIC_RELAXED, __HIP_MEMORY_SCOPE_AGENT);
}
__device__ __forceinline__ void st_agent_u64(unsigned long long* p,
                                             unsigned long long v) {
  __hip_atomic_store(p, v, __ATOMIC_RELAXED, __HIP_MEMORY_SCOPE_AGENT);
}
__device__ __forceinline__ unsigned long long
ld_agent_u64(const unsigned long long* p) {
  return __hip_atomic_load(p, __ATOMIC_RELAXED, __HIP_MEMORY_SCOPE_AGENT);
}

// ---------------------------------------------------------------------------
// Recurrence: 256 persistent WGs x 576 threads (1/CU, 9 waves).
// WAVE SPECIALIZATION (R17 lesson: probe logic interleaved into compute waves
// either breaks the compiler's FMA/LDS pipeline (sched_barrier pins, -30%)
// or mistimes the samples (R11-R16 residual ~1us/step)):
//   waves 0-7 (512 thr): COMPUTE ONLY. Group g=bid&15 owns batches {2g,2g+1};
//     member m=bid>>4 owns rows [m*64,+64); thread (jrel=tid>>3,l8=tid&7):
//     row j, k-chunk [l8*136,+136), 68 float2 stationary weights. Per phase:
//     pure matvec + tanh + producer stores (ring packet tag t+1, slot t&3 +
//     agent rate_all). No probes, no pins — compiler schedules freely.
//   wave 8 (64 lanes): PROBER. Lane l owns rows [16l,16l+16). During C0(t)
//     it polls batch-1's tag-t packets (stored at end of C1(t-1) — prober
//     catches visibility as it lands, concurrent with compute) and commits
//     r+x into lds[1]; during C1(t) it polls batch-0's tag-(t+1) packets.
//     Commit is always one full phase before consumption.
// Step time -> max(compute, exchange) instead of sum.
// Barriers: lgkm-only s_barrier per phase; both branches execute exactly 2
// per iteration (counts match; s_barrier is per-wave arrival). Prober's
// ds_writes drain via lgkmcnt(0) before its barrier.
// Liveness: prober polls are the only waits, on unconditionally-stored
// monotone tags => deadlock-free by the R10-R16 induction. 4-slot ring,
// WG lead bound <= 2 < 4 => no lap hazard. Ring zeroed per call (tags>=1).
// ---------------------------------------------------------------------------
__global__ __launch_bounds__(576, 1) void rnn_recur(
    const float* __restrict__ input_sig, const float* __restrict__ rate0,
    const float* __restrict__ i2h_w, const float* __restrict__ i2h_b,
    const float* __restrict__ h2h_w, const float* __restrict__ h2h_b,
    float* __restrict__ rate_all, unsigned long long* __restrict__ ring)
{
  const int tid = threadIdx.x;
  const int bid = blockIdx.x;
  const int g   = bid & (NG - 1);
  const int bG  = g * 2;

  __shared__ float lds[2][BSTR];   // [batch][padded chunks + x tail]

  // ---- init: r_{-1} = rate0 and x_0 for both batches (plain cached loads)
  if (tid < 512) {
    const int b = tid >> 8, u4 = tid & 255;
    const int k0 = u4 * 4, c = k0 / CH, off = k0 - c * CH;
    float4 v = *(const float4*)(rate0 + (long long)(bG + b) * H + k0);
    *(float4*)&lds[b][c * CHP + off] = v;
    if (tid < 32) {
      const int b2 = tid >> 4, iq = tid & 15;
      float4 u = *(const float4*)(input_sig + (long long)(bG + b2) * I_ + iq * 4);
      *(float4*)&lds[b2][7 * CHP + 72 + iq * 4] = u;
    }
  }
  __syncthreads();

  unsigned long long* ringG = ring + (long long)g * (4 * 2 * 1024);

  if (tid < 512) {
    // ================= COMPUTE WAVES (0-7) ===============================
    const int m    = bid >> 4;
    const int l8   = tid & 7;
    const int jrel = tid >> 3;
    const int j    = m * 64 + jrel;

    v2f w2[68];
#pragma unroll
    for (int q = 0; q < 68; ++q) {
      const int k = l8 * CH + q * 2;
      w2[q] = (k < H) ? *(const v2f*)(h2h_w + (long long)j * H + k)
                      : *(const v2f*)(i2h_w + (long long)j * I_ + (k - H));
    }
    const float bsum = h2h_b[j] + i2h_b[j];
    const int posj = (j / CH) * CHP + (j % CH);

    auto phase = [&](int b, int t) {
      const float* Rb = &lds[b][0];
      v2f acc2 = {0.f, 0.f};
#pragma unroll
      for (int q = 0; q < 34; ++q) {
        const v4f rv = *(const v4f*)&Rb[l8 * CHP + q * 4];
        const v2f rlo = __builtin_shufflevector(rv, rv, 0, 1);
        const v2f rhi = __builtin_shufflevector(rv, rv, 2, 3);
        acc2 = __builtin_elementwise_fma(w2[2 * q],     rlo, acc2);
        acc2 = __builtin_elementwise_fma(w2[2 * q + 1], rhi, acc2);
      }
      float acc = acc2.x + acc2.y;
      acc += __shfl_xor(acc, 4, 64);
      acc += __shfl_xor(acc, 2, 64);
      acc += __shfl_xor(acc, 1, 64);
      if (l8 == 0) {
        const float pre  = acc + bsum;
        const float rold = Rb[posj];
        const float rnew = 0.9f * rold + 0.1f * tanhf(pre);
        const unsigned long long pkt =
            ((unsigned long long)(unsigned)(t + 1) << 32) |
            (unsigned long long)__float_as_uint(rnew);
        st_agent_u64(&ringG[((long long)((t & 3) * 2 + b) << 10) + j], pkt);
        st_agent_f32(&rate_all[((long long)t * B + bG + b) * H + j], rnew);
      }
    };

    for (int t = 0; t < T; ++t) {
      phase(0, t);
      asm volatile("s_waitcnt lgkmcnt(0)\n\ts_barrier" ::: "memory");
      phase(1, t);
      asm volatile("s_waitcnt lgkmcnt(0)\n\ts_barrier" ::: "memory");
    }
  } else {
    // ================= PROBER WAVE (8) ===================================
    const int l = tid - 512;          // lane 0..63, owns rows [16l, 16l+16)

    // poll 16 tagged packets at p (tag), commit values into lds[dst] rows
    // [16l,16l+16), plus x float4 (lanes 0-15) into the x tail.
    auto probe_commit = [&](const unsigned long long* p, unsigned tag,
                            int dst, const float* xsrc) {
      float4 xv;
      if (l < 16) xv = *(const float4*)(xsrc + l * 4);
      unsigned long long v0, v1, v2, v3, v4, v5, v6, v7;
      unsigned long long v8, v9, va, vb, vc, vd, ve, vf;
      bool ok;
      do {
        v0 = ld_agent_u64(p + 0);  v1 = ld_agent_u64(p + 1);
        v2 = ld_agent_u64(p + 2);  v3 = ld_agent_u64(p + 3);
        v4 = ld_agent_u64(p + 4);  v5 = ld_agent_u64(p + 5);
        v6 = ld_agent_u64(p + 6);  v7 = ld_agent_u64(p + 7);
        v8 = ld_agent_u64(p + 8);  v9 = ld_agent_u64(p + 9);
        va = ld_agent_u64(p + 10); vb = ld_agent_u64(p + 11);
        vc = ld_agent_u64(p + 12); vd = ld_agent_u64(p + 13);
        ve = ld_agent_u64(p + 14); vf = ld_agent_u64(p + 15);
        ok =  ((unsigned)(v0 >> 32) == tag) & ((unsigned)(v1 >> 32) == tag)
            & ((unsigned)(v2 >> 32) == tag) & ((unsigned)(v3 >> 32) == tag)
            & ((unsigned)(v4 >> 32) == tag) & ((unsigned)(v5 >> 32) == tag)
            & ((unsigned)(v6 >> 32) == tag) & ((unsigned)(v7 >> 32) == tag)
            & ((unsigned)(v8 >> 32) == tag) & ((unsigned)(v9 >> 32) == tag)
            & ((unsigned)(va >> 32) == tag) & ((unsigned)(vb >> 32) == tag)
            & ((unsigned)(vc >> 32) == tag) & ((unsigned)(vd >> 32) == tag)
            & ((unsigned)(ve >> 32) == tag) & ((unsigned)(vf >> 32) == tag);
      } while (!ok);
      unsigned long long vv[16] = {v0,v1,v2,v3,v4,v5,v6,v7,
                                   v8,v9,va,vb,vc,vd,ve,vf};
#pragma unroll
      for (int i = 0; i < 16; ++i) {
        const int row = 16 * l + i;
        lds[dst][(row / CH) * CHP + (row % CH)] =
            __uint_as_float((unsigned)vv[i]);
      }
      if (l < 16) *(float4*)&lds[dst][7 * CHP + 72 + l * 4] = xv;
    };

    for (int t = 0; t < T; ++t) {
      // phase A (compute does C0(t)): b1's r_t-inputs = tag-t packets
      // stored at end of C1(t-1); commit lds[1] for consumption at C1(t).
      if (t >= 1) {
        probe_commit(
            &ringG[((long long)((((t - 1) & 3) * 2) + 1) << 10) + 16 * l],
            (unsigned)t, 1,
            input_sig + ((long long)t * B + bG + 1) * I_);
      }
      asm volatile("s_waitcnt lgkmcnt(0)\n\ts_barrier" ::: "memory");
      // phase B (compute does C1(t)): b0's tag-(t+1) packets stored at end
      // of C0(t); commit lds[0] for consumption at C0(t+1).
      if (t + 1 < T) {
        probe_commit(
            &ringG[((long long)((t & 3) * 2) << 10) + 16 * l],
            (unsigned)(t + 1), 0,
            input_sig + ((long long)(t + 1) * B + bG) * I_);
      }
      asm volatile("s_waitcnt lgkmcnt(0)\n\ts_barrier" ::: "memory");
    }
  }
}

// ---------------------------------------------------------------------------
// Readout: C[32768,72] = rate_all[32768,1024] x [h2o_w;h2o_ctx_w]^T + bias
// ---------------------------------------------------------------------------
__global__ __launch_bounds__(256) void rnn_readout(
    const float* __restrict__ rate_all,
    const float* __restrict__ h2o_w, const float* __restrict__ h2o_b,
    const float* __restrict__ h2o_ctx_w, const float* __restrict__ h2o_ctx_b,
    float* __restrict__ out0, float* __restrict__ out1)
{
  constexpr int RB = 128;
  constexpr int HC = 128;
  constexpr int SR = HC + 1;
  __shared__ float rl[RB * SR];
  __shared__ float wl[72 * SR];

  const int tid = threadIdx.x;
  const long long row0 = (long long)blockIdx.x * RB;
  const int rb = tid & 31, og = tid >> 5;

  float acc[4][9];
#pragma unroll
  for (int c = 0; c < 4; ++c)
#pragma unroll
    for (int i = 0; i < 9; ++i) acc[c][i] = 0.f;

  for (int hc = 0; hc < H / HC; ++hc) {
#pragma unroll
    for (int i = 0; i < 16; ++i) {
      const int q = i * 256 + tid;
      const int row = q >> 5, hq = q & 31;
      float4 v = *(const float4*)(rate_all + (row0 + row) * H + hc * HC + hq * 4);
      float* d = &rl[row * SR + hq * 4];
      d[0] = v.x; d[1] = v.y; d[2] = v.z; d[3] = v.w;
    }
#pragma unroll
    for (int i = 0; i < 9; ++i) {
      const int q = i * 256 + tid;
      const int o = q >> 5, hq = q & 31;
      const float* src = (o < OF) ? (h2o_w + (long long)o * H)
                                  : (h2o_ctx_w + (long long)(o - OF) * H);
      float4 v = *(const float4*)(src + hc * HC + hq * 4);
      float* d = &wl[o * SR + hq * 4];
      d[0] = v.x; d[1] = v.y; d[2] = v.z; d[3] = v.w;
    }
    __syncthreads();

#pragma unroll 4
    for (int h = 0; h < HC; ++h) {
      const float r0 = rl[(rb)      * SR + h];
      const float r1 = rl[(rb + 32) * SR + h];
      const float r2 = rl[(rb + 64) * SR + h];
      const float r3 = rl[(rb + 96) * SR + h];
#pragma unroll
      for (int i = 0; i < 9; ++i) {
        const float wv = wl[(og * 9 + i) * SR + h];
        acc[0][i] = fmaf(r0, wv, acc[0][i]);
        acc[1][i] = fmaf(r1, wv, acc[1][i]);
        acc[2][i] = fmaf(r2, wv, acc[2][i]);
        acc[3][i] = fmaf(r3, wv, acc[3][i]);
      }
    }
    __syncthreads();
  }

#pragma unroll
  for (int c = 0; c < 4; ++c) {
    const long long row = row0 + rb + 32 * c;
#pragma unroll
    for (int i = 0; i < 9; ++i) {
      const int o = og * 9 + i;
      if (o < OF) out0[row * OF + o] = acc[c][i] + h2o_b[o];
      else        out1[row * OC + (o - OF)] = acc[c][i] + h2o_ctx_b[o - OF];
    }
  }
}

extern "C" void kernel_launch(void* const* d_in, const int* in_sizes, int n_in,
                              void* d_out, int out_size, void* d_ws, size_t ws_size,
                              hipStream_t stream) {
  (void)in_sizes; (void)n_in; (void)d_ws; (void)ws_size; (void)out_size;
  const float* input_sig = (const float*)d_in[0];
  const float* rate0     = (const float*)d_in[1];
  const float* i2h_w     = (const float*)d_in[2];
  const float* i2h_b     = (const float*)d_in[3];
  const float* h2h_w     = (const float*)d_in[4];
  const float* h2h_b     = (const float*)d_in[5];
  const float* h2o_w     = (const float*)d_in[6];
  const float* h2o_b     = (const float*)d_in[7];
  const float* h2o_ctx_w = (const float*)d_in[8];
  const float* h2o_ctx_b = (const float*)d_in[9];

  float* out      = (float*)d_out;
  float* out0     = out;
  float* out1     = out + OUT1_OFF;
  float* rate_all = out + OUT2_OFF;
  // Tagged 4-slot ring in the first 1 MB of out0 (overwritten by readout).
  unsigned long long* ring = (unsigned long long*)d_out;

  // Zero the ring EVERY call: expected tags are >=1, so zero never matches;
  // stale tags from a previous call/graph-replay would otherwise alias.
  hipMemsetAsync(ring, 0, (size_t)RING_U64 * 8, stream);
  hipLaunchKernelGGL(rnn_recur, dim3(NG * NM), dim3(576), 0, stream,
                     input_sig, rate0, i2h_w, i2h_b, h2h_w, h2h_b,
                     rate_all, ring);
  hipLaunchKernelGGL(rnn_readout, dim3(256), dim3(256), 0, stream,
                     rate_all, h2o_w, h2o_b, h2o_ctx_w, h2o_ctx_b, out0, out1);
}